// Round 9
// baseline (358.325 us; speedup 1.0000x reference)
//
#include <hip/hip_runtime.h>
#include <hip/hip_fp16.h>

// Problem constants
#define NV   20000
#define KK   3
#define INF  150
#define HH   64
#define OO   128
#define PT   80
#define KTOT 5120      // 80 bins * 64 h
#define NB   80        // vertices per geo block (250 tiles x 2 ks = 500 blocks)
#define RS   72        // pch v-row stride, halves (64 + 8 pad)
#define CB   (NB * RS) // 5760 halves = 11520 B per buffer
#define XS   168       // x/W1 LDS col stride, halves (prep kernel)
#define NBIN 40        // bins per K-slice
#define CPS  41        // conn bin-dim stride (40 + 1 pad -> v0 reads spread banks)

typedef _Float16 fh8 __attribute__((ext_vector_type(8)));   // MFMA A/B frag (4 VGPRs)
typedef __attribute__((ext_vector_type(4))) float f32x4;    // MFMA C/D frag
typedef __attribute__((ext_vector_type(8))) unsigned short u16x8;

__device__ __forceinline__ unsigned short f2h(float f) {
    return __half_as_ushort(__float2half(f));
}
__device__ __forceinline__ _Float16 u2h(unsigned short u) {
    union { unsigned short s; _Float16 h; } c; c.s = u; return c.h;
}

// ---------------------------------------------------------------------------
// Fused prep kernel (v16, unchanged).
// Blocks 0..127: transpose Wg[o] -> W2 [S][o][kk] fp16 via LDS.
// Blocks 128..752: h = relu(x @ W1^T) -> fp16, 32 rows/block via MFMA.
// ---------------------------------------------------------------------------
__global__ __launch_bounds__(256) void prep_kernel(
    const float* __restrict__ Wg, const float* __restrict__ x,
    const float* __restrict__ W1, unsigned short* __restrict__ W2,
    unsigned short* __restrict__ hb) {
    __shared__ __align__(16) unsigned char smem[32256];
    const int tid = threadIdx.x;

    if (blockIdx.x < 128) {
        float* lds = (float*)smem;                 // 64*81 words
        const int o = blockIdx.x;
        const float* src = Wg + o * KTOT;
        for (int e = tid; e < KTOT / 4; e += 256) {
            const float4 v4 = ((const float4*)src)[e];
            const int t = e * 4;
            const int h = t / 80, bin = t - h * 80;
            lds[h * 81 + bin]     = v4.x;
            lds[h * 81 + bin + 1] = v4.y;
            lds[h * 81 + bin + 2] = v4.z;
            lds[h * 81 + bin + 3] = v4.w;
        }
        __syncthreads();
        for (int e = tid; e < KTOT / 2; e += 256) {
            const int t = e * 2;
            const unsigned int h0 = f2h(lds[(t & 63) * 81 + (t >> 6)]);
            const unsigned int h1 = f2h(lds[((t + 1) & 63) * 81 + ((t + 1) >> 6)]);
            *(unsigned int*)(W2 + (t >> 5) * 4096 + o * 32 + (t & 31)) =
                h0 | (h1 << 16);
        }
        return;
    }

    unsigned short* xs = (unsigned short*)smem;    // 32*168
    unsigned short* ws = xs + 32 * XS;             // 64*168
    const int n0 = (blockIdx.x - 128) * 32;

    {
        const float2* x2 = (const float2*)(x + (size_t)n0 * INF);
        for (int e = tid; e < 32 * (INF / 2); e += 256) {
            const int f = e * 2;
            const int r = f / INF, c = f - r * INF;
            const float2 v = x2[e];
            const unsigned int p =
                (unsigned int)f2h(v.x) | ((unsigned int)f2h(v.y) << 16);
            *(unsigned int*)(xs + r * XS + c) = p;
        }
    }
    for (int e = tid; e < 32 * 9; e += 256) {
        const int r = e / 9, c2 = e - r * 9;
        *(unsigned int*)(xs + r * XS + 150 + c2 * 2) = 0;
    }
    {
        const float2* w2p = (const float2*)W1;
        for (int e = tid; e < 64 * (INF / 2); e += 256) {
            const int f = e * 2;
            const int r = f / INF, c = f - r * INF;
            const float2 v = w2p[e];
            const unsigned int p =
                (unsigned int)f2h(v.x) | ((unsigned int)f2h(v.y) << 16);
            *(unsigned int*)(ws + r * XS + c) = p;
        }
    }
    for (int e = tid; e < 64 * 9; e += 256) {
        const int r = e / 9, c2 = e - r * 9;
        *(unsigned int*)(ws + r * XS + 150 + c2 * 2) = 0;
    }
    __syncthreads();

    const int wv   = tid >> 6;
    const int lane = tid & 63;
    const int q    = lane >> 4;
    const int r16  = lane & 15;
    const int o0   = wv * 16;

    f32x4 acc0 = {0.f, 0.f, 0.f, 0.f};
    f32x4 acc1 = acc0;
    #pragma unroll
    for (int s = 0; s < 5; s++) {
        const int kb = s * 32 + q * 8;
        fh8 a0 = *(const fh8*)(xs + r16 * XS + kb);
        fh8 a1 = *(const fh8*)(xs + (16 + r16) * XS + kb);
        fh8 b  = *(const fh8*)(ws + (o0 + r16) * XS + kb);
        acc0 = __builtin_amdgcn_mfma_f32_16x16x32_f16(a0, b, acc0, 0, 0, 0);
        acc1 = __builtin_amdgcn_mfma_f32_16x16x32_f16(a1, b, acc1, 0, 0, 0);
    }
    #pragma unroll
    for (int r = 0; r < 4; r++) {
        float v0 = acc0[r] > 0.f ? acc0[r] : 0.f;
        float v1 = acc1[r] > 0.f ? acc1[r] : 0.f;
        hb[(n0 + q * 4 + r) * HH + o0 + r16]      = f2h(v0);
        hb[(n0 + 16 + q * 4 + r) * HH + o0 + r16] = f2h(v1);
    }
}

// ---------------------------------------------------------------------------
// Geo kernel v20: v18 main loop (EXACT) + last-block-done fused norm.
// R8 post-mortem: v19's deep pipeline regressed 64->101us -- VGPR=68 shows
// the compiler demoted the named gather sets to scratch (lambda-by-ref
// defeated SROA; rule-#20 failure mode). Reverted. v18's main loop is the
// proven floor (63-64us over 5 structural variants); the remaining lever
// is deleting the norm LAUNCH: both ks blocks write fp32 partials (ks0 ->
// out, ks1 -> part1), threadfence, atomicAdd on a per-tile counter
// (memset to 0 each launch); the second finisher reads its partner's
// partial and runs v17's proven in-block bias+rsqrt epilogue.
// Deterministic: v = (other_mem + mine_reg) + bg -- both partials exact
// fp32, IEEE add commutative -> identical result regardless of winner.
// No spinning, no residency assumption (G16-safe).
// ---------------------------------------------------------------------------
__global__ __launch_bounds__(512, 2) void geo_kernel(
    const int*   __restrict__ conn_idx, const float* __restrict__ conn_w,
    const unsigned short* __restrict__ W2, const unsigned short* __restrict__ hb,
    float* __restrict__ out, float* __restrict__ part1,
    int* __restrict__ cnt, const float* __restrict__ bg) {
    __shared__ __align__(16) unsigned short pch[2 * CB];        // 23040 B
    __shared__ __align__(16) unsigned short cp[NB * CPS * 8];   // 52480 B
    __shared__ int isLast;

    const int tid  = threadIdx.x;
    const int ks   = blockIdx.x & 1;             // K-slice 0..1
    const int tile = blockIdx.x >> 1;            // 0..249
    const int n0   = tile * NB;
    const int wv   = tid >> 6;                   // wave 0..7 = o-frag
    const int lane = tid & 63;
    const int q    = lane >> 4;
    const int r16  = lane & 15;
    const int j8   = tid & 7;                    // 16B segment of h row
    const int v0   = tid >> 3;                   // vertex 0..63 (lo also +64)
    const bool lo  = (v0 < 16);                  // rows 64..79
    const int bbase = ks * NBIN;
    const int Sbase = ks * (NBIN * 2);           // first 32-k step

    // All 40 bins of conn -> LDS, packed cp[v][cc] = [i0,i1,i2,w0,w1,w2,0,0]
    for (int e = tid; e < NB * NBIN; e += 512) {
        const int v = e / NBIN, cc = e - v * NBIN;
        const int g = (n0 + v) * (PT * KK) + (bbase + cc) * KK;
        u16x8 pk;
        pk[0] = (unsigned short)conn_idx[g];
        pk[1] = (unsigned short)conn_idx[g + 1];
        pk[2] = (unsigned short)conn_idx[g + 2];
        pk[3] = f2h(conn_w[g]);
        pk[4] = f2h(conn_w[g + 1]);
        pk[5] = f2h(conn_w[g + 2]);
        pk[6] = 0; pk[7] = 0;
        *(u16x8*)(cp + (v * CPS + cc) * 8) = pk;
    }

    f32x4 acc[5];
    #pragma unroll
    for (int m = 0; m < 5; m++) acc[m] = (f32x4){0.f, 0.f, 0.f, 0.f};

    u16x8 pa, pc;        // packed conn for rows v0 and (lo) v0+64
    fh8   hva0, hva1, hva2, hvc0, hvc1, hvc2;

    auto loadg = [&](int cc) {                   // conn b128 + 3..6 gathers
        pa = *(const u16x8*)(cp + (v0 * CPS + cc) * 8);
        hva0 = *(const fh8*)(hb + (int)pa[0] * HH + j8 * 8);
        hva1 = *(const fh8*)(hb + (int)pa[1] * HH + j8 * 8);
        hva2 = *(const fh8*)(hb + (int)pa[2] * HH + j8 * 8);
        if (lo) {                                // wave-uniform (waves 0..1)
            pc = *(const u16x8*)(cp + ((v0 + 64) * CPS + cc) * 8);
            hvc0 = *(const fh8*)(hb + (int)pc[0] * HH + j8 * 8);
            hvc1 = *(const fh8*)(hb + (int)pc[1] * HH + j8 * 8);
            hvc2 = *(const fh8*)(hb + (int)pc[2] * HH + j8 * 8);
        }
    };
    auto cwr = [&](unsigned short* buf) {        // combine + 1..2 LDS b128 writes
        const _Float16 a0 = u2h(pa[3]), a1 = u2h(pa[4]), a2 = u2h(pa[5]);
        const fh8 A0 = {a0, a0, a0, a0, a0, a0, a0, a0};
        const fh8 A1 = {a1, a1, a1, a1, a1, a1, a1, a1};
        const fh8 A2 = {a2, a2, a2, a2, a2, a2, a2, a2};
        fh8 ra = hva0 * A0 + hva1 * A1 + hva2 * A2;
        *(fh8*)(buf + v0 * RS + j8 * 8) = ra;
        if (lo) {
            const _Float16 c0 = u2h(pc[3]), c1 = u2h(pc[4]), c2 = u2h(pc[5]);
            const fh8 C0 = {c0, c0, c0, c0, c0, c0, c0, c0};
            const fh8 C1 = {c1, c1, c1, c1, c1, c1, c1, c1};
            const fh8 C2 = {c2, c2, c2, c2, c2, c2, c2, c2};
            fh8 rc = hvc0 * C0 + hvc1 * C1 + hvc2 * C2;
            *(fh8*)(buf + (v0 + 64) * RS + j8 * 8) = rc;
        }
    };
    auto mfmaph = [&](const unsigned short* buf, int cc) {   // 10 MFMA/wave
        const unsigned short* wp =
            W2 + (Sbase + cc * 2) * 4096 + (wv * 16 + r16) * 32 + q * 8;
        const fh8 bf0 = *(const fh8*)(wp);
        const fh8 bf1 = *(const fh8*)(wp + 4096);
        #pragma unroll
        for (int s = 0; s < 2; s++) {
            const int ao = s * 32 + q * 8;
            const fh8 bf = s ? bf1 : bf0;
            #pragma unroll
            for (int m = 0; m < 5; m++) {
                fh8 af = *(const fh8*)(buf + (m * 16 + r16) * RS + ao);
                acc[m] = __builtin_amdgcn_mfma_f32_16x16x32_f16(af, bf, acc[m], 0, 0, 0);
            }
        }
    };

    __syncthreads();                             // cp visible

    // Prologue: bin 0 staged into buffer 0
    loadg(0);
    cwr(pch);
    __syncthreads();

    #pragma unroll 1
    for (int cc = 0; cc < NBIN; cc++) {
        if (cc + 1 < NBIN) loadg(cc + 1);        // gathers in flight over MFMA
        mfmaph(&pch[(cc & 1) * CB], cc);
        if (cc + 1 < NBIN) cwr(&pch[((cc + 1) & 1) * CB]);
        __syncthreads();
    }

    // Partial store (both ks in exact fp32). 250*80 = 20000 -> no guards.
    {
        float* dst = (ks == 0) ? out : part1;
        #pragma unroll
        for (int m = 0; m < 5; m++) {
            const int rb = n0 + m * 16 + q * 4;
            #pragma unroll
            for (int r = 0; r < 4; r++)
                dst[(rb + r) * OO + wv * 16 + r16] = acc[m][r];
        }
    }

    // Last-block-done handshake.
    __threadfence();                             // partial visible device-wide
    if (tid == 0)
        isLast = (atomicAdd(&cnt[tile], 1) == 1);
    __syncthreads();                             // isLast block-uniform
    if (!isLast) return;
    __threadfence();                             // acquire partner's stores

    // -------- fused epilogue (v17-proven): v = other + mine + bg;
    //          out = v * rsqrt(sum v^2). pch is dead -> reduction scratch.
    const float* other = (ks == 0) ? part1 : out;
    float* sums = (float*)pch;                   // [80][33] partial sumsq
    float* rsy  = sums + NB * 33;                // [80] rsqrt per row

    const float bias = bg[wv * 16 + r16];
    float v[5][4];
    float ps[5][4];
    #pragma unroll
    for (int m = 0; m < 5; m++) {
        const int rb = n0 + m * 16 + q * 4;
        #pragma unroll
        for (int r = 0; r < 4; r++) {
            v[m][r] = other[(rb + r) * OO + wv * 16 + r16] + acc[m][r] + bias;
            float s2 = v[m][r] * v[m][r];
            s2 += __shfl_xor(s2, 1, 16);         // reduce over r16 within
            s2 += __shfl_xor(s2, 2, 16);         //   4-lane groups
            ps[m][r] = s2;
        }
    }
    if ((r16 & 3) == 0) {                        // 4 writers per q-group
        #pragma unroll
        for (int m = 0; m < 5; m++)
            #pragma unroll
            for (int r = 0; r < 4; r++)
                sums[(m * 16 + q * 4 + r) * 33 + wv * 4 + (r16 >> 2)] = ps[m][r];
    }
    __syncthreads();
    if (tid < NB) {                              // final 32-way reduce per row
        float tot = 0.f;
        #pragma unroll
        for (int c = 0; c < 32; c++) tot += sums[tid * 33 + c];
        rsy[tid] = rsqrtf(tot);
    }
    __syncthreads();
    #pragma unroll
    for (int m = 0; m < 5; m++) {
        const int rb = n0 + m * 16 + q * 4;
        #pragma unroll
        for (int r = 0; r < 4; r++) {
            const float rs = rsy[m * 16 + q * 4 + r];   // LDS broadcast
            out[(rb + r) * OO + wv * 16 + r16] = v[m][r] * rs;
        }
    }
}

// ---------------------------------------------------------------------------
extern "C" void kernel_launch(void* const* d_in, const int* in_sizes, int n_in,
                              void* d_out, int out_size, void* d_ws, size_t ws_size,
                              hipStream_t stream) {
    const float* x        = (const float*)d_in[0];
    const int*   conn_idx = (const int*)  d_in[1];
    const float* conn_w   = (const float*)d_in[2];
    const float* W1       = (const float*)d_in[3];
    const float* Wg       = (const float*)d_in[4];
    const float* bg       = (const float*)d_in[5];
    float*       out      = (float*)d_out;

    unsigned short* W2    = (unsigned short*)d_ws;         // 655,360 fp16 (1.31 MB)
    unsigned short* hb    = W2 + OO * KTOT;                // 1,280,000 fp16 (2.56 MB)
    float*          part1 = (float*)(hb + NV * HH);        // 2,560,000 f32 (10.24 MB)
    int*            cnt   = (int*)(part1 + NV * OO);       // 250 ints

    hipMemsetAsync(cnt, 0, 250 * sizeof(int), stream);     // graph-safe reset
    hipLaunchKernelGGL(prep_kernel, dim3(128 + NV / 32), dim3(256), 0, stream,
                       Wg, x, W1, W2, hb);
    hipLaunchKernelGGL(geo_kernel, dim3(2 * (NV / NB)), dim3(512), 0, stream,
                       conn_idx, conn_w, W2, hb, out, part1, cnt, bg);
}

// Round 10
// 204.510 us; speedup vs baseline: 1.7521x; 1.7521x over previous
//
#include <hip/hip_runtime.h>
#include <hip/hip_fp16.h>

// Problem constants
#define NV   20000
#define KK   3
#define INF  150
#define HH   64
#define OO   128
#define PT   80
#define KTOT 5120      // 80 bins * 64 h
#define NB   80        // vertices per geo block (v21: 250 tiles x 4 ks = 1000 blocks)
#define RS   72        // pch v-row stride, halves (64 + 8 pad)
#define CB   (NB * RS) // 5760 halves = 11520 B per buffer
#define XS   168       // x/W1 LDS col stride, halves (prep kernel)
#define NBIN 20        // bins per K-slice
#define NCH  10        // bins per conn chunk (LDS holds one chunk at a time)
#define CPS  11        // conn bin-dim stride (10 + 1 pad -> v0 reads spread banks)

typedef _Float16 fh8 __attribute__((ext_vector_type(8)));   // MFMA A/B frag (4 VGPRs)
typedef __attribute__((ext_vector_type(4))) float f32x4;    // MFMA C/D frag
typedef __attribute__((ext_vector_type(8))) unsigned short u16x8;

__device__ __forceinline__ unsigned short f2h(float f) {
    return __half_as_ushort(__float2half(f));
}
__device__ __forceinline__ float h2f(unsigned short u) {
    return __half2float(__ushort_as_half(u));
}
__device__ __forceinline__ _Float16 u2h(unsigned short u) {
    union { unsigned short s; _Float16 h; } c; c.s = u; return c.h;
}

// ---------------------------------------------------------------------------
// Fused prep kernel (v16, unchanged).
// Blocks 0..127: transpose Wg[o] -> W2 [S][o][kk] fp16 via LDS.
// Blocks 128..752: h = relu(x @ W1^T) -> fp16, 32 rows/block via MFMA.
// ---------------------------------------------------------------------------
__global__ __launch_bounds__(256) void prep_kernel(
    const float* __restrict__ Wg, const float* __restrict__ x,
    const float* __restrict__ W1, unsigned short* __restrict__ W2,
    unsigned short* __restrict__ hb) {
    __shared__ __align__(16) unsigned char smem[32256];
    const int tid = threadIdx.x;

    if (blockIdx.x < 128) {
        float* lds = (float*)smem;                 // 64*81 words
        const int o = blockIdx.x;
        const float* src = Wg + o * KTOT;
        for (int e = tid; e < KTOT / 4; e += 256) {
            const float4 v4 = ((const float4*)src)[e];
            const int t = e * 4;
            const int h = t / 80, bin = t - h * 80;
            lds[h * 81 + bin]     = v4.x;
            lds[h * 81 + bin + 1] = v4.y;
            lds[h * 81 + bin + 2] = v4.z;
            lds[h * 81 + bin + 3] = v4.w;
        }
        __syncthreads();
        for (int e = tid; e < KTOT / 2; e += 256) {
            const int t = e * 2;
            const unsigned int h0 = f2h(lds[(t & 63) * 81 + (t >> 6)]);
            const unsigned int h1 = f2h(lds[((t + 1) & 63) * 81 + ((t + 1) >> 6)]);
            *(unsigned int*)(W2 + (t >> 5) * 4096 + o * 32 + (t & 31)) =
                h0 | (h1 << 16);
        }
        return;
    }

    unsigned short* xs = (unsigned short*)smem;    // 32*168
    unsigned short* ws = xs + 32 * XS;             // 64*168
    const int n0 = (blockIdx.x - 128) * 32;

    {
        const float2* x2 = (const float2*)(x + (size_t)n0 * INF);
        for (int e = tid; e < 32 * (INF / 2); e += 256) {
            const int f = e * 2;
            const int r = f / INF, c = f - r * INF;
            const float2 v = x2[e];
            const unsigned int p =
                (unsigned int)f2h(v.x) | ((unsigned int)f2h(v.y) << 16);
            *(unsigned int*)(xs + r * XS + c) = p;
        }
    }
    for (int e = tid; e < 32 * 9; e += 256) {
        const int r = e / 9, c2 = e - r * 9;
        *(unsigned int*)(xs + r * XS + 150 + c2 * 2) = 0;
    }
    {
        const float2* w2p = (const float2*)W1;
        for (int e = tid; e < 64 * (INF / 2); e += 256) {
            const int f = e * 2;
            const int r = f / INF, c = f - r * INF;
            const float2 v = w2p[e];
            const unsigned int p =
                (unsigned int)f2h(v.x) | ((unsigned int)f2h(v.y) << 16);
            *(unsigned int*)(ws + r * XS + c) = p;
        }
    }
    for (int e = tid; e < 64 * 9; e += 256) {
        const int r = e / 9, c2 = e - r * 9;
        *(unsigned int*)(ws + r * XS + 150 + c2 * 2) = 0;
    }
    __syncthreads();

    const int wv   = tid >> 6;
    const int lane = tid & 63;
    const int q    = lane >> 4;
    const int r16  = lane & 15;
    const int o0   = wv * 16;

    f32x4 acc0 = {0.f, 0.f, 0.f, 0.f};
    f32x4 acc1 = acc0;
    #pragma unroll
    for (int s = 0; s < 5; s++) {
        const int kb = s * 32 + q * 8;
        fh8 a0 = *(const fh8*)(xs + r16 * XS + kb);
        fh8 a1 = *(const fh8*)(xs + (16 + r16) * XS + kb);
        fh8 b  = *(const fh8*)(ws + (o0 + r16) * XS + kb);
        acc0 = __builtin_amdgcn_mfma_f32_16x16x32_f16(a0, b, acc0, 0, 0, 0);
        acc1 = __builtin_amdgcn_mfma_f32_16x16x32_f16(a1, b, acc1, 0, 0, 0);
    }
    #pragma unroll
    for (int r = 0; r < 4; r++) {
        float v0 = acc0[r] > 0.f ? acc0[r] : 0.f;
        float v1 = acc1[r] > 0.f ? acc1[r] : 0.f;
        hb[(n0 + q * 4 + r) * HH + o0 + r16]      = f2h(v0);
        hb[(n0 + 16 + q * 4 + r) * HH + o0 + r16] = f2h(v1);
    }
}

// ---------------------------------------------------------------------------
// Geo kernel v21: v18 inner loop (EXACT) at 4 blocks/CU co-residency.
// R9 post-mortem: v20's last-block-done norm regressed 64->276us -- the
// per-block device-scope __threadfence() compiles to L2 writeback/inval
// on gfx950's non-coherent XCD L2s, evicting W2/hb for all co-resident
// blocks; every gather fell to L3 latency. Device fences in the hot
// kernel are poison. Reverted to the 3-kernel shape.
// Theory: geo is stall-bound (no pipe >60%); v14/v18's 2 blocks/CU was
// GRID-limited (500/256), never capacity-limited. v21 doubles resident
// blocks: NB=80, split-K x4 -> 1000 blocks <= 1024 capacity (single
// round, 4/CU). LDS trimmed to 37.1 KB: pch 23 KB + chunked conn
// (10 bins, CPS=11 -> 14.1 KB). Chunk1 loads global->LDS at the bin-9
// drain (once per block, ~1us exposed, behind the proven v14 barrier
// pattern) -- no parked VGPRs, keeps VGPR ~52 so 8 waves/SIMD fit under
// the launch_bounds(512,8) 64-VGPR cap (4 blocks needs VGPR<=64!).
// Gather/W2/store patterns bit-identical to v18.
// Deterministic partials: ks=0 -> fp32 d_out, ks>=1 -> fp16 parts[ks-1].
// ---------------------------------------------------------------------------
__global__ __launch_bounds__(512, 8) void geo_kernel(
    const int*   __restrict__ conn_idx, const float* __restrict__ conn_w,
    const unsigned short* __restrict__ W2, const unsigned short* __restrict__ hb,
    float* __restrict__ out, unsigned short* __restrict__ parts) {
    __shared__ __align__(16) unsigned short pch[2 * CB];        // 23040 B
    __shared__ __align__(16) unsigned short cp[NB * CPS * 8];   // 14080 B

    const int tid  = threadIdx.x;
    const int ks   = blockIdx.x & 3;             // K-slice 0..3
    const int n0   = (blockIdx.x >> 2) * NB;     // 0..249 * 80
    const int wv   = tid >> 6;                   // wave 0..7 = o-frag
    const int lane = tid & 63;
    const int q    = lane >> 4;
    const int r16  = lane & 15;
    const int j8   = tid & 7;                    // 16B segment of h row
    const int v0   = tid >> 3;                   // vertex 0..63 (lo also +64)
    const bool lo  = (v0 < 16);                  // rows 64..79
    const int bbase = ks * NBIN;
    const int Sbase = ks * (NBIN * 2);           // first 32-k step

    // Conn chunk loader: bins [c0, c0+NCH) -> cp slots [0, NCH).
    // cp[(v*CPS+bb)*8] = [i0,i1,i2,w0,w1,w2,0,0]; 800 entries / 512 thr.
    auto packchunk = [&](int c0) {
        for (int e = tid; e < NB * NCH; e += 512) {
            const int v = e / NCH, cc = e - v * NCH;
            const int g = (n0 + v) * (PT * KK) + (bbase + c0 + cc) * KK;
            u16x8 pk;
            pk[0] = (unsigned short)conn_idx[g];
            pk[1] = (unsigned short)conn_idx[g + 1];
            pk[2] = (unsigned short)conn_idx[g + 2];
            pk[3] = f2h(conn_w[g]);
            pk[4] = f2h(conn_w[g + 1]);
            pk[5] = f2h(conn_w[g + 2]);
            pk[6] = 0; pk[7] = 0;
            *(u16x8*)(cp + (v * CPS + cc) * 8) = pk;
        }
    };

    packchunk(0);                                // chunk0: bins 0..9

    f32x4 acc[5];
    #pragma unroll
    for (int m = 0; m < 5; m++) acc[m] = (f32x4){0.f, 0.f, 0.f, 0.f};

    u16x8 pa, pc;        // packed conn for rows v0 and (lo) v0+64
    fh8   hva0, hva1, hva2, hvc0, hvc1, hvc2;

    auto loadg = [&](int cc) {                   // conn b128 + 3..6 gathers
        const int bb = (cc >= NCH) ? cc - NCH : cc;
        pa = *(const u16x8*)(cp + (v0 * CPS + bb) * 8);
        hva0 = *(const fh8*)(hb + (int)pa[0] * HH + j8 * 8);
        hva1 = *(const fh8*)(hb + (int)pa[1] * HH + j8 * 8);
        hva2 = *(const fh8*)(hb + (int)pa[2] * HH + j8 * 8);
        if (lo) {                                // wave-uniform (waves 0..1)
            pc = *(const u16x8*)(cp + ((v0 + 64) * CPS + bb) * 8);
            hvc0 = *(const fh8*)(hb + (int)pc[0] * HH + j8 * 8);
            hvc1 = *(const fh8*)(hb + (int)pc[1] * HH + j8 * 8);
            hvc2 = *(const fh8*)(hb + (int)pc[2] * HH + j8 * 8);
        }
    };
    auto cwr = [&](unsigned short* buf) {        // combine + 1..2 LDS b128 writes
        const _Float16 a0 = u2h(pa[3]), a1 = u2h(pa[4]), a2 = u2h(pa[5]);
        const fh8 A0 = {a0, a0, a0, a0, a0, a0, a0, a0};
        const fh8 A1 = {a1, a1, a1, a1, a1, a1, a1, a1};
        const fh8 A2 = {a2, a2, a2, a2, a2, a2, a2, a2};
        fh8 ra = hva0 * A0 + hva1 * A1 + hva2 * A2;
        *(fh8*)(buf + v0 * RS + j8 * 8) = ra;
        if (lo) {
            const _Float16 c0 = u2h(pc[3]), c1 = u2h(pc[4]), c2 = u2h(pc[5]);
            const fh8 C0 = {c0, c0, c0, c0, c0, c0, c0, c0};
            const fh8 C1 = {c1, c1, c1, c1, c1, c1, c1, c1};
            const fh8 C2 = {c2, c2, c2, c2, c2, c2, c2, c2};
            fh8 rc = hvc0 * C0 + hvc1 * C1 + hvc2 * C2;
            *(fh8*)(buf + (v0 + 64) * RS + j8 * 8) = rc;
        }
    };
    auto mfmaph = [&](const unsigned short* buf, int cc) {   // 10 MFMA/wave
        const unsigned short* wp =
            W2 + (Sbase + cc * 2) * 4096 + (wv * 16 + r16) * 32 + q * 8;
        const fh8 bf0 = *(const fh8*)(wp);
        const fh8 bf1 = *(const fh8*)(wp + 4096);
        #pragma unroll
        for (int s = 0; s < 2; s++) {
            const int ao = s * 32 + q * 8;
            const fh8 bf = s ? bf1 : bf0;
            #pragma unroll
            for (int m = 0; m < 5; m++) {
                fh8 af = *(const fh8*)(buf + (m * 16 + r16) * RS + ao);
                acc[m] = __builtin_amdgcn_mfma_f32_16x16x32_f16(af, bf, acc[m], 0, 0, 0);
            }
        }
    };

    __syncthreads();                             // cp chunk0 visible

    // Prologue: bin 0 staged into buffer 0
    loadg(0);
    cwr(pch);
    __syncthreads();

    #pragma unroll 1
    for (int cc = 0; cc < NBIN; cc++) {
        if (cc == NCH - 1) {
            // Overwrite cp with chunk1 (bins 10..19), direct global->LDS.
            // Safe: last chunk0 read was loadg(9) in iter 8, before the
            // iter-8-end barrier. Exposed global latency: once per block.
            packchunk(NCH);
            __syncthreads();                     // chunk1 visible for loadg(10+)
        }
        if (cc + 1 < NBIN) loadg(cc + 1);        // gathers in flight over MFMA
        mfmaph(&pch[(cc & 1) * CB], cc);
        if (cc + 1 < NBIN) cwr(&pch[((cc + 1) & 1) * CB]);
        __syncthreads();
    }

    // Partial store. D layout: row = q*4+reg, col = r16. 250*80 = 20000
    // exactly -> no guards. One writer per element per stage.
    if (ks == 0) {
        #pragma unroll
        for (int m = 0; m < 5; m++) {
            const int rb = n0 + m * 16 + q * 4;
            #pragma unroll
            for (int r = 0; r < 4; r++)
                out[(rb + r) * OO + wv * 16 + r16] = acc[m][r];
        }
    } else {
        unsigned short* pp = parts + (ks - 1) * (NV * OO);
        #pragma unroll
        for (int m = 0; m < 5; m++) {
            const int rb = n0 + m * 16 + q * 4;
            #pragma unroll
            for (int r = 0; r < 4; r++)
                pp[(rb + r) * OO + wv * 16 + r16] = f2h(acc[m][r]);
        }
    }
}

// ---------------------------------------------------------------------------
// Epilogue (v16 3-part version): v = out + p0+p1+p2 + bg;
// out = v*rsqrt(sum v^2). 32 rows/block, 8 threads/row.
// ---------------------------------------------------------------------------
__global__ __launch_bounds__(256) void norm_kernel(
    float* __restrict__ out, const unsigned short* __restrict__ parts,
    const float* __restrict__ bg) {
    const int tid  = threadIdx.x;
    const int n    = blockIdx.x * 32 + (tid >> 3);
    const int l    = tid & 7;
    const int base = n * OO + l * 16;            // 16-float col slice

    float4 o4[4];
    #pragma unroll
    for (int i = 0; i < 4; i++)
        o4[i] = *(const float4*)(out + base + i * 4);

    u16x8 p[3][2];
    #pragma unroll
    for (int s = 0; s < 3; s++) {
        p[s][0] = *(const u16x8*)(parts + s * (NV * OO) + base);
        p[s][1] = *(const u16x8*)(parts + s * (NV * OO) + base + 8);
    }

    float4 b4[4];
    #pragma unroll
    for (int i = 0; i < 4; i++)
        b4[i] = *(const float4*)(bg + l * 16 + i * 4);

    float v[16];
    float s = 0.f;
    #pragma unroll
    for (int i = 0; i < 16; i++) {
        const float ov = (i & 3) == 0 ? o4[i >> 2].x :
                         (i & 3) == 1 ? o4[i >> 2].y :
                         (i & 3) == 2 ? o4[i >> 2].z : o4[i >> 2].w;
        const float bv = (i & 3) == 0 ? b4[i >> 2].x :
                         (i & 3) == 1 ? b4[i >> 2].y :
                         (i & 3) == 2 ? b4[i >> 2].z : b4[i >> 2].w;
        v[i] = ov + h2f(p[0][i >> 3][i & 7]) + h2f(p[1][i >> 3][i & 7]) +
               h2f(p[2][i >> 3][i & 7]) + bv;
        s += v[i] * v[i];
    }
    for (int off = 4; off; off >>= 1) s += __shfl_down(s, off, 8);
    const float r = rsqrtf(__shfl(s, 0, 8));
    #pragma unroll
    for (int i = 0; i < 4; i++) {
        float4 w = {v[i * 4] * r, v[i * 4 + 1] * r,
                    v[i * 4 + 2] * r, v[i * 4 + 3] * r};
        *(float4*)(out + base + i * 4) = w;
    }
}

// ---------------------------------------------------------------------------
extern "C" void kernel_launch(void* const* d_in, const int* in_sizes, int n_in,
                              void* d_out, int out_size, void* d_ws, size_t ws_size,
                              hipStream_t stream) {
    const float* x        = (const float*)d_in[0];
    const int*   conn_idx = (const int*)  d_in[1];
    const float* conn_w   = (const float*)d_in[2];
    const float* W1       = (const float*)d_in[3];
    const float* Wg       = (const float*)d_in[4];
    const float* bg       = (const float*)d_in[5];
    float*       out      = (float*)d_out;

    unsigned short* W2    = (unsigned short*)d_ws;         // 655,360 fp16 (1.31 MB)
    unsigned short* hb    = W2 + OO * KTOT;                // 1,280,000 fp16 (2.56 MB)
    unsigned short* parts = hb + NV * HH;                  // 3 x 2,560,000 fp16 (15.4 MB)

    hipLaunchKernelGGL(prep_kernel, dim3(128 + NV / 32), dim3(256), 0, stream,
                       Wg, x, W1, W2, hb);
    hipLaunchKernelGGL(geo_kernel, dim3(4 * (NV / NB)), dim3(512), 0, stream,
                       conn_idx, conn_w, W2, hb, out, parts);
    hipLaunchKernelGGL(norm_kernel, dim3(NV / 32), dim3(256), 0, stream,
                       out, parts, bg);
}

// Round 11
// 165.324 us; speedup vs baseline: 2.1674x; 1.2370x over previous
//
#include <hip/hip_runtime.h>
#include <hip/hip_fp16.h>

// Problem constants
#define NV   20000
#define KK   3
#define INF  150
#define HH   64
#define OO   128
#define PT   80
#define KTOT 5120      // 80 bins * 64 h
#define NB   80        // vertices per geo block (250 tiles x 4 ks = 1000 blocks)
#define RS   72        // pch v-row stride, halves (64 + 8 pad)
#define CB   (NB * RS) // 5760 halves = 11520 B per buffer
#define XS   168       // x/W1 LDS col stride, halves (prep kernel)
#define NBIN 20        // bins per K-slice
#define NCH  10        // bins per conn chunk (LDS holds one chunk at a time)
#define CPS  11        // conn bin-dim stride (10 + 1 pad -> v0 reads spread banks)

typedef _Float16 fh8 __attribute__((ext_vector_type(8)));   // MFMA A/B frag (4 VGPRs)
typedef __attribute__((ext_vector_type(4))) float f32x4;    // MFMA C/D frag
typedef __attribute__((ext_vector_type(8))) unsigned short u16x8;

__device__ __forceinline__ unsigned short f2h(float f) {
    return __half_as_ushort(__float2half(f));
}
__device__ __forceinline__ float h2f(unsigned short u) {
    return __half2float(__ushort_as_half(u));
}
__device__ __forceinline__ _Float16 u2h(unsigned short u) {
    union { unsigned short s; _Float16 h; } c; c.s = u; return c.h;
}

// ---------------------------------------------------------------------------
// Fused prep kernel (v16, unchanged).
// Blocks 0..127: transpose Wg[o] -> W2 [S][o][kk] fp16 via LDS.
// Blocks 128..752: h = relu(x @ W1^T) -> fp16, 32 rows/block via MFMA.
// ---------------------------------------------------------------------------
__global__ __launch_bounds__(256) void prep_kernel(
    const float* __restrict__ Wg, const float* __restrict__ x,
    const float* __restrict__ W1, unsigned short* __restrict__ W2,
    unsigned short* __restrict__ hb) {
    __shared__ __align__(16) unsigned char smem[32256];
    const int tid = threadIdx.x;

    if (blockIdx.x < 128) {
        float* lds = (float*)smem;                 // 64*81 words
        const int o = blockIdx.x;
        const float* src = Wg + o * KTOT;
        for (int e = tid; e < KTOT / 4; e += 256) {
            const float4 v4 = ((const float4*)src)[e];
            const int t = e * 4;
            const int h = t / 80, bin = t - h * 80;
            lds[h * 81 + bin]     = v4.x;
            lds[h * 81 + bin + 1] = v4.y;
            lds[h * 81 + bin + 2] = v4.z;
            lds[h * 81 + bin + 3] = v4.w;
        }
        __syncthreads();
        for (int e = tid; e < KTOT / 2; e += 256) {
            const int t = e * 2;
            const unsigned int h0 = f2h(lds[(t & 63) * 81 + (t >> 6)]);
            const unsigned int h1 = f2h(lds[((t + 1) & 63) * 81 + ((t + 1) >> 6)]);
            *(unsigned int*)(W2 + (t >> 5) * 4096 + o * 32 + (t & 31)) =
                h0 | (h1 << 16);
        }
        return;
    }

    unsigned short* xs = (unsigned short*)smem;    // 32*168
    unsigned short* ws = xs + 32 * XS;             // 64*168
    const int n0 = (blockIdx.x - 128) * 32;

    {
        const float2* x2 = (const float2*)(x + (size_t)n0 * INF);
        for (int e = tid; e < 32 * (INF / 2); e += 256) {
            const int f = e * 2;
            const int r = f / INF, c = f - r * INF;
            const float2 v = x2[e];
            const unsigned int p =
                (unsigned int)f2h(v.x) | ((unsigned int)f2h(v.y) << 16);
            *(unsigned int*)(xs + r * XS + c) = p;
        }
    }
    for (int e = tid; e < 32 * 9; e += 256) {
        const int r = e / 9, c2 = e - r * 9;
        *(unsigned int*)(xs + r * XS + 150 + c2 * 2) = 0;
    }
    {
        const float2* w2p = (const float2*)W1;
        for (int e = tid; e < 64 * (INF / 2); e += 256) {
            const int f = e * 2;
            const int r = f / INF, c = f - r * INF;
            const float2 v = w2p[e];
            const unsigned int p =
                (unsigned int)f2h(v.x) | ((unsigned int)f2h(v.y) << 16);
            *(unsigned int*)(ws + r * XS + c) = p;
        }
    }
    for (int e = tid; e < 64 * 9; e += 256) {
        const int r = e / 9, c2 = e - r * 9;
        *(unsigned int*)(ws + r * XS + 150 + c2 * 2) = 0;
    }
    __syncthreads();

    const int wv   = tid >> 6;
    const int lane = tid & 63;
    const int q    = lane >> 4;
    const int r16  = lane & 15;
    const int o0   = wv * 16;

    f32x4 acc0 = {0.f, 0.f, 0.f, 0.f};
    f32x4 acc1 = acc0;
    #pragma unroll
    for (int s = 0; s < 5; s++) {
        const int kb = s * 32 + q * 8;
        fh8 a0 = *(const fh8*)(xs + r16 * XS + kb);
        fh8 a1 = *(const fh8*)(xs + (16 + r16) * XS + kb);
        fh8 b  = *(const fh8*)(ws + (o0 + r16) * XS + kb);
        acc0 = __builtin_amdgcn_mfma_f32_16x16x32_f16(a0, b, acc0, 0, 0, 0);
        acc1 = __builtin_amdgcn_mfma_f32_16x16x32_f16(a1, b, acc1, 0, 0, 0);
    }
    #pragma unroll
    for (int r = 0; r < 4; r++) {
        float v0 = acc0[r] > 0.f ? acc0[r] : 0.f;
        float v1 = acc1[r] > 0.f ? acc1[r] : 0.f;
        hb[(n0 + q * 4 + r) * HH + o0 + r16]      = f2h(v0);
        hb[(n0 + 16 + q * 4 + r) * HH + o0 + r16] = f2h(v1);
    }
}

// ---------------------------------------------------------------------------
// Geo kernel v22: v21 retried WITHOUT the register straitjacket.
// R10 post-mortem: v21's launch_bounds(512,8) made the allocator target
// VGPR=32 and spill everything to scratch: FETCH 40->122 MB, WRITE
// 26->114 MB (+190 MB scratch traffic), geo 107us. The 4-blocks/CU TLP
// experiment was VOIDED by spills, not refuted -- occupancy did hit 78%.
// v22: identical kernel, launch_bounds(512,4) (VGPR cap 128, no forced
// spill). The v18-class body compiles to ~52 VGPR, which rounds to the
// 64-VGPR hardware granule -> HW can still co-schedule 4 blocks/CU
// (32 waves = CU max; LDS 4 x 37.4 KB = 149.5 <= 160 KB) if it has the
// slots. Clean test of: does 32 waves/CU fill the barrier stalls that
// pin geo at ~63us?  Gate: VGPR_Count <= 64 in the counter CSV.
// Deterministic partials: ks=0 -> fp32 d_out, ks>=1 -> fp16 parts[ks-1].
// ---------------------------------------------------------------------------
__global__ __launch_bounds__(512, 4) void geo_kernel(
    const int*   __restrict__ conn_idx, const float* __restrict__ conn_w,
    const unsigned short* __restrict__ W2, const unsigned short* __restrict__ hb,
    float* __restrict__ out, unsigned short* __restrict__ parts) {
    __shared__ __align__(16) unsigned short pch[2 * CB];        // 23040 B
    __shared__ __align__(16) unsigned short cp[NB * CPS * 8];   // 14080 B

    const int tid  = threadIdx.x;
    const int ks   = blockIdx.x & 3;             // K-slice 0..3
    const int n0   = (blockIdx.x >> 2) * NB;     // 0..249 * 80
    const int wv   = tid >> 6;                   // wave 0..7 = o-frag
    const int lane = tid & 63;
    const int q    = lane >> 4;
    const int r16  = lane & 15;
    const int j8   = tid & 7;                    // 16B segment of h row
    const int v0   = tid >> 3;                   // vertex 0..63 (lo also +64)
    const bool lo  = (v0 < 16);                  // rows 64..79
    const int bbase = ks * NBIN;
    const int Sbase = ks * (NBIN * 2);           // first 32-k step

    // Conn chunk loader: bins [c0, c0+NCH) -> cp slots [0, NCH).
    // cp[(v*CPS+bb)*8] = [i0,i1,i2,w0,w1,w2,0,0]; 800 entries / 512 thr.
    auto packchunk = [&](int c0) {
        for (int e = tid; e < NB * NCH; e += 512) {
            const int v = e / NCH, cc = e - v * NCH;
            const int g = (n0 + v) * (PT * KK) + (bbase + c0 + cc) * KK;
            u16x8 pk;
            pk[0] = (unsigned short)conn_idx[g];
            pk[1] = (unsigned short)conn_idx[g + 1];
            pk[2] = (unsigned short)conn_idx[g + 2];
            pk[3] = f2h(conn_w[g]);
            pk[4] = f2h(conn_w[g + 1]);
            pk[5] = f2h(conn_w[g + 2]);
            pk[6] = 0; pk[7] = 0;
            *(u16x8*)(cp + (v * CPS + cc) * 8) = pk;
        }
    };

    packchunk(0);                                // chunk0: bins 0..9

    f32x4 acc[5];
    #pragma unroll
    for (int m = 0; m < 5; m++) acc[m] = (f32x4){0.f, 0.f, 0.f, 0.f};

    u16x8 pa, pc;        // packed conn for rows v0 and (lo) v0+64
    fh8   hva0, hva1, hva2, hvc0, hvc1, hvc2;

    auto loadg = [&](int cc) {                   // conn b128 + 3..6 gathers
        const int bb = (cc >= NCH) ? cc - NCH : cc;
        pa = *(const u16x8*)(cp + (v0 * CPS + bb) * 8);
        hva0 = *(const fh8*)(hb + (int)pa[0] * HH + j8 * 8);
        hva1 = *(const fh8*)(hb + (int)pa[1] * HH + j8 * 8);
        hva2 = *(const fh8*)(hb + (int)pa[2] * HH + j8 * 8);
        if (lo) {                                // wave-uniform (waves 0..1)
            pc = *(const u16x8*)(cp + ((v0 + 64) * CPS + bb) * 8);
            hvc0 = *(const fh8*)(hb + (int)pc[0] * HH + j8 * 8);
            hvc1 = *(const fh8*)(hb + (int)pc[1] * HH + j8 * 8);
            hvc2 = *(const fh8*)(hb + (int)pc[2] * HH + j8 * 8);
        }
    };
    auto cwr = [&](unsigned short* buf) {        // combine + 1..2 LDS b128 writes
        const _Float16 a0 = u2h(pa[3]), a1 = u2h(pa[4]), a2 = u2h(pa[5]);
        const fh8 A0 = {a0, a0, a0, a0, a0, a0, a0, a0};
        const fh8 A1 = {a1, a1, a1, a1, a1, a1, a1, a1};
        const fh8 A2 = {a2, a2, a2, a2, a2, a2, a2, a2};
        fh8 ra = hva0 * A0 + hva1 * A1 + hva2 * A2;
        *(fh8*)(buf + v0 * RS + j8 * 8) = ra;
        if (lo) {
            const _Float16 c0 = u2h(pc[3]), c1 = u2h(pc[4]), c2 = u2h(pc[5]);
            const fh8 C0 = {c0, c0, c0, c0, c0, c0, c0, c0};
            const fh8 C1 = {c1, c1, c1, c1, c1, c1, c1, c1};
            const fh8 C2 = {c2, c2, c2, c2, c2, c2, c2, c2};
            fh8 rc = hvc0 * C0 + hvc1 * C1 + hvc2 * C2;
            *(fh8*)(buf + (v0 + 64) * RS + j8 * 8) = rc;
        }
    };
    auto mfmaph = [&](const unsigned short* buf, int cc) {   // 10 MFMA/wave
        const unsigned short* wp =
            W2 + (Sbase + cc * 2) * 4096 + (wv * 16 + r16) * 32 + q * 8;
        const fh8 bf0 = *(const fh8*)(wp);
        const fh8 bf1 = *(const fh8*)(wp + 4096);
        #pragma unroll
        for (int s = 0; s < 2; s++) {
            const int ao = s * 32 + q * 8;
            const fh8 bf = s ? bf1 : bf0;
            #pragma unroll
            for (int m = 0; m < 5; m++) {
                fh8 af = *(const fh8*)(buf + (m * 16 + r16) * RS + ao);
                acc[m] = __builtin_amdgcn_mfma_f32_16x16x32_f16(af, bf, acc[m], 0, 0, 0);
            }
        }
    };

    __syncthreads();                             // cp chunk0 visible

    // Prologue: bin 0 staged into buffer 0
    loadg(0);
    cwr(pch);
    __syncthreads();

    #pragma unroll 1
    for (int cc = 0; cc < NBIN; cc++) {
        if (cc == NCH - 1) {
            // Overwrite cp with chunk1 (bins 10..19), direct global->LDS.
            // Safe: last chunk0 read was loadg(9) in iter 8, before the
            // iter-8-end barrier. Exposed global latency: once per block.
            packchunk(NCH);
            __syncthreads();                     // chunk1 visible for loadg(10+)
        }
        if (cc + 1 < NBIN) loadg(cc + 1);        // gathers in flight over MFMA
        mfmaph(&pch[(cc & 1) * CB], cc);
        if (cc + 1 < NBIN) cwr(&pch[((cc + 1) & 1) * CB]);
        __syncthreads();
    }

    // Partial store. D layout: row = q*4+reg, col = r16. 250*80 = 20000
    // exactly -> no guards. One writer per element per stage.
    if (ks == 0) {
        #pragma unroll
        for (int m = 0; m < 5; m++) {
            const int rb = n0 + m * 16 + q * 4;
            #pragma unroll
            for (int r = 0; r < 4; r++)
                out[(rb + r) * OO + wv * 16 + r16] = acc[m][r];
        }
    } else {
        unsigned short* pp = parts + (ks - 1) * (NV * OO);
        #pragma unroll
        for (int m = 0; m < 5; m++) {
            const int rb = n0 + m * 16 + q * 4;
            #pragma unroll
            for (int r = 0; r < 4; r++)
                pp[(rb + r) * OO + wv * 16 + r16] = f2h(acc[m][r]);
        }
    }
}

// ---------------------------------------------------------------------------
// Epilogue (v16 3-part version): v = out + p0+p1+p2 + bg;
// out = v*rsqrt(sum v^2). 32 rows/block, 8 threads/row.
// ---------------------------------------------------------------------------
__global__ __launch_bounds__(256) void norm_kernel(
    float* __restrict__ out, const unsigned short* __restrict__ parts,
    const float* __restrict__ bg) {
    const int tid  = threadIdx.x;
    const int n    = blockIdx.x * 32 + (tid >> 3);
    const int l    = tid & 7;
    const int base = n * OO + l * 16;            // 16-float col slice

    float4 o4[4];
    #pragma unroll
    for (int i = 0; i < 4; i++)
        o4[i] = *(const float4*)(out + base + i * 4);

    u16x8 p[3][2];
    #pragma unroll
    for (int s = 0; s < 3; s++) {
        p[s][0] = *(const u16x8*)(parts + s * (NV * OO) + base);
        p[s][1] = *(const u16x8*)(parts + s * (NV * OO) + base + 8);
    }

    float4 b4[4];
    #pragma unroll
    for (int i = 0; i < 4; i++)
        b4[i] = *(const float4*)(bg + l * 16 + i * 4);

    float v[16];
    float s = 0.f;
    #pragma unroll
    for (int i = 0; i < 16; i++) {
        const float ov = (i & 3) == 0 ? o4[i >> 2].x :
                         (i & 3) == 1 ? o4[i >> 2].y :
                         (i & 3) == 2 ? o4[i >> 2].z : o4[i >> 2].w;
        const float bv = (i & 3) == 0 ? b4[i >> 2].x :
                         (i & 3) == 1 ? b4[i >> 2].y :
                         (i & 3) == 2 ? b4[i >> 2].z : b4[i >> 2].w;
        v[i] = ov + h2f(p[0][i >> 3][i & 7]) + h2f(p[1][i >> 3][i & 7]) +
               h2f(p[2][i >> 3][i & 7]) + bv;
        s += v[i] * v[i];
    }
    for (int off = 4; off; off >>= 1) s += __shfl_down(s, off, 8);
    const float r = rsqrtf(__shfl(s, 0, 8));
    #pragma unroll
    for (int i = 0; i < 4; i++) {
        float4 w = {v[i * 4] * r, v[i * 4 + 1] * r,
                    v[i * 4 + 2] * r, v[i * 4 + 3] * r};
        *(float4*)(out + base + i * 4) = w;
    }
}

// ---------------------------------------------------------------------------
extern "C" void kernel_launch(void* const* d_in, const int* in_sizes, int n_in,
                              void* d_out, int out_size, void* d_ws, size_t ws_size,
                              hipStream_t stream) {
    const float* x        = (const float*)d_in[0];
    const int*   conn_idx = (const int*)  d_in[1];
    const float* conn_w   = (const float*)d_in[2];
    const float* W1       = (const float*)d_in[3];
    const float* Wg       = (const float*)d_in[4];
    const float* bg       = (const float*)d_in[5];
    float*       out      = (float*)d_out;

    unsigned short* W2    = (unsigned short*)d_ws;         // 655,360 fp16 (1.31 MB)
    unsigned short* hb    = W2 + OO * KTOT;                // 1,280,000 fp16 (2.56 MB)
    unsigned short* parts = hb + NV * HH;                  // 3 x 2,560,000 fp16 (15.4 MB)

    hipLaunchKernelGGL(prep_kernel, dim3(128 + NV / 32), dim3(256), 0, stream,
                       Wg, x, W1, W2, hb);
    hipLaunchKernelGGL(geo_kernel, dim3(4 * (NV / NB)), dim3(512), 0, stream,
                       conn_idx, conn_w, W2, hb, out, parts);
    hipLaunchKernelGGL(norm_kernel, dim3(NV / 32), dim3(256), 0, stream,
                       out, parts, bg);
}

// Round 12
// 159.047 us; speedup vs baseline: 2.2530x; 1.0395x over previous
//
#include <hip/hip_runtime.h>
#include <hip/hip_fp16.h>

// Problem constants
#define NV   20000
#define KK   3
#define INF  150
#define HH   64
#define OO   128
#define PT   80
#define KTOT 5120      // 80 bins * 64 h
#define NB   80        // vertices per geo block (250 tiles x 2 ks = 500 blocks)
#define RS   72        // pch v-row stride, halves (64 + 8 pad)
#define CB   (NB * RS) // 5760 halves = 11520 B per buffer
#define XS   168       // x/W1 LDS col stride, halves (prep kernel)
#define NBIN 40        // bins per K-slice
#define CPS  41        // conn bin-dim stride (40 + 1 pad -> v0 reads spread banks)

typedef _Float16 fh8 __attribute__((ext_vector_type(8)));   // MFMA A/B frag (4 VGPRs)
typedef __attribute__((ext_vector_type(4))) float f32x4;    // MFMA C/D frag
typedef __attribute__((ext_vector_type(8))) unsigned short u16x8;

__device__ __forceinline__ unsigned short f2h(float f) {
    return __half_as_ushort(__float2half(f));
}
__device__ __forceinline__ float h2f(unsigned short u) {
    return __half2float(__ushort_as_half(u));
}
__device__ __forceinline__ _Float16 u2h(unsigned short u) {
    union { unsigned short s; _Float16 h; } c; c.s = u; return c.h;
}

// ---------------------------------------------------------------------------
// Fused prep kernel (v16, unchanged).
// Blocks 0..127: transpose Wg[o] -> W2 [S][o][kk] fp16 via LDS.
// Blocks 128..752: h = relu(x @ W1^T) -> fp16, 32 rows/block via MFMA.
// ---------------------------------------------------------------------------
__global__ __launch_bounds__(256) void prep_kernel(
    const float* __restrict__ Wg, const float* __restrict__ x,
    const float* __restrict__ W1, unsigned short* __restrict__ W2,
    unsigned short* __restrict__ hb) {
    __shared__ __align__(16) unsigned char smem[32256];
    const int tid = threadIdx.x;

    if (blockIdx.x < 128) {
        float* lds = (float*)smem;                 // 64*81 words
        const int o = blockIdx.x;
        const float* src = Wg + o * KTOT;
        for (int e = tid; e < KTOT / 4; e += 256) {
            const float4 v4 = ((const float4*)src)[e];
            const int t = e * 4;
            const int h = t / 80, bin = t - h * 80;
            lds[h * 81 + bin]     = v4.x;
            lds[h * 81 + bin + 1] = v4.y;
            lds[h * 81 + bin + 2] = v4.z;
            lds[h * 81 + bin + 3] = v4.w;
        }
        __syncthreads();
        for (int e = tid; e < KTOT / 2; e += 256) {
            const int t = e * 2;
            const unsigned int h0 = f2h(lds[(t & 63) * 81 + (t >> 6)]);
            const unsigned int h1 = f2h(lds[((t + 1) & 63) * 81 + ((t + 1) >> 6)]);
            *(unsigned int*)(W2 + (t >> 5) * 4096 + o * 32 + (t & 31)) =
                h0 | (h1 << 16);
        }
        return;
    }

    unsigned short* xs = (unsigned short*)smem;    // 32*168
    unsigned short* ws = xs + 32 * XS;             // 64*168
    const int n0 = (blockIdx.x - 128) * 32;

    {
        const float2* x2 = (const float2*)(x + (size_t)n0 * INF);
        for (int e = tid; e < 32 * (INF / 2); e += 256) {
            const int f = e * 2;
            const int r = f / INF, c = f - r * INF;
            const float2 v = x2[e];
            const unsigned int p =
                (unsigned int)f2h(v.x) | ((unsigned int)f2h(v.y) << 16);
            *(unsigned int*)(xs + r * XS + c) = p;
        }
    }
    for (int e = tid; e < 32 * 9; e += 256) {
        const int r = e / 9, c2 = e - r * 9;
        *(unsigned int*)(xs + r * XS + 150 + c2 * 2) = 0;
    }
    {
        const float2* w2p = (const float2*)W1;
        for (int e = tid; e < 64 * (INF / 2); e += 256) {
            const int f = e * 2;
            const int r = f / INF, c = f - r * INF;
            const float2 v = w2p[e];
            const unsigned int p =
                (unsigned int)f2h(v.x) | ((unsigned int)f2h(v.y) << 16);
            *(unsigned int*)(ws + r * XS + c) = p;
        }
    }
    for (int e = tid; e < 64 * 9; e += 256) {
        const int r = e / 9, c2 = e - r * 9;
        *(unsigned int*)(ws + r * XS + 150 + c2 * 2) = 0;
    }
    __syncthreads();

    const int wv   = tid >> 6;
    const int lane = tid & 63;
    const int q    = lane >> 4;
    const int r16  = lane & 15;
    const int o0   = wv * 16;

    f32x4 acc0 = {0.f, 0.f, 0.f, 0.f};
    f32x4 acc1 = acc0;
    #pragma unroll
    for (int s = 0; s < 5; s++) {
        const int kb = s * 32 + q * 8;
        fh8 a0 = *(const fh8*)(xs + r16 * XS + kb);
        fh8 a1 = *(const fh8*)(xs + (16 + r16) * XS + kb);
        fh8 b  = *(const fh8*)(ws + (o0 + r16) * XS + kb);
        acc0 = __builtin_amdgcn_mfma_f32_16x16x32_f16(a0, b, acc0, 0, 0, 0);
        acc1 = __builtin_amdgcn_mfma_f32_16x16x32_f16(a1, b, acc1, 0, 0, 0);
    }
    #pragma unroll
    for (int r = 0; r < 4; r++) {
        float v0 = acc0[r] > 0.f ? acc0[r] : 0.f;
        float v1 = acc1[r] > 0.f ? acc1[r] : 0.f;
        hb[(n0 + q * 4 + r) * HH + o0 + r16]      = f2h(v0);
        hb[(n0 + 16 + q * 4 + r) * HH + o0 + r16] = f2h(v1);
    }
}

// ---------------------------------------------------------------------------
// Geo kernel v23 == v18 (proven session best, geo 63-64us, total 158.2us).
// R11 post-mortem closes the ledger: with VGPR=52 and no spills, 4-block/CU
// capacity did NOT raise occupancy or speed (68.8us, conn FETCH +33 MB from
// the x4 bin split). Against this v18 baseline every structural direction
// measured worse: traffic -38% -> 0 (R7), wave-grid -> -16% (R4), deep
// pipeline -> -60% (R8), 1-block/CU fusion -> -60% (R6), device-fence
// fusion -> -330% (R9), TLP 4/CU -> -8% (R10/R11). All pipes < 60% busy:
// this is a balanced local optimum (barrier cadence + gather latency + LDS
// + TCP mutually hidden at 2 blocks/CU), not a hardware roofline.
// Split-K x2, NB=80, 40 bins/block, 500 blocks single round, 2/CU.
// Deterministic partials: ks=0 -> fp32 d_out, ks=1 -> fp16 parts.
// ---------------------------------------------------------------------------
__global__ __launch_bounds__(512, 2) void geo_kernel(
    const int*   __restrict__ conn_idx, const float* __restrict__ conn_w,
    const unsigned short* __restrict__ W2, const unsigned short* __restrict__ hb,
    float* __restrict__ out, unsigned short* __restrict__ parts) {
    __shared__ __align__(16) unsigned short pch[2 * CB];        // 23040 B
    __shared__ __align__(16) unsigned short cp[NB * CPS * 8];   // 52480 B

    const int tid  = threadIdx.x;
    const int ks   = blockIdx.x & 1;             // K-slice 0..1
    const int n0   = (blockIdx.x >> 1) * NB;     // 0..249 * 80
    const int wv   = tid >> 6;                   // wave 0..7 = o-frag
    const int lane = tid & 63;
    const int q    = lane >> 4;
    const int r16  = lane & 15;
    const int j8   = tid & 7;                    // 16B segment of h row
    const int v0   = tid >> 3;                   // vertex 0..63 (lo also +64)
    const bool lo  = (v0 < 16);                  // rows 64..79
    const int bbase = ks * NBIN;
    const int Sbase = ks * (NBIN * 2);           // first 32-k step

    // All 40 bins of conn -> LDS, packed cp[v][cc] = [i0,i1,i2,w0,w1,w2,0,0]
    for (int e = tid; e < NB * NBIN; e += 512) {
        const int v = e / NBIN, cc = e - v * NBIN;
        const int g = (n0 + v) * (PT * KK) + (bbase + cc) * KK;
        u16x8 pk;
        pk[0] = (unsigned short)conn_idx[g];
        pk[1] = (unsigned short)conn_idx[g + 1];
        pk[2] = (unsigned short)conn_idx[g + 2];
        pk[3] = f2h(conn_w[g]);
        pk[4] = f2h(conn_w[g + 1]);
        pk[5] = f2h(conn_w[g + 2]);
        pk[6] = 0; pk[7] = 0;
        *(u16x8*)(cp + (v * CPS + cc) * 8) = pk;
    }

    f32x4 acc[5];
    #pragma unroll
    for (int m = 0; m < 5; m++) acc[m] = (f32x4){0.f, 0.f, 0.f, 0.f};

    u16x8 pa, pc;        // packed conn for rows v0 and (lo) v0+64
    fh8   hva0, hva1, hva2, hvc0, hvc1, hvc2;

    auto loadg = [&](int cc) {                   // conn b128 + 3..6 gathers
        pa = *(const u16x8*)(cp + (v0 * CPS + cc) * 8);
        hva0 = *(const fh8*)(hb + (int)pa[0] * HH + j8 * 8);
        hva1 = *(const fh8*)(hb + (int)pa[1] * HH + j8 * 8);
        hva2 = *(const fh8*)(hb + (int)pa[2] * HH + j8 * 8);
        if (lo) {                                // wave-uniform (waves 0..1)
            pc = *(const u16x8*)(cp + ((v0 + 64) * CPS + cc) * 8);
            hvc0 = *(const fh8*)(hb + (int)pc[0] * HH + j8 * 8);
            hvc1 = *(const fh8*)(hb + (int)pc[1] * HH + j8 * 8);
            hvc2 = *(const fh8*)(hb + (int)pc[2] * HH + j8 * 8);
        }
    };
    auto cwr = [&](unsigned short* buf) {        // combine + 1..2 LDS b128 writes
        const _Float16 a0 = u2h(pa[3]), a1 = u2h(pa[4]), a2 = u2h(pa[5]);
        const fh8 A0 = {a0, a0, a0, a0, a0, a0, a0, a0};
        const fh8 A1 = {a1, a1, a1, a1, a1, a1, a1, a1};
        const fh8 A2 = {a2, a2, a2, a2, a2, a2, a2, a2};
        fh8 ra = hva0 * A0 + hva1 * A1 + hva2 * A2;
        *(fh8*)(buf + v0 * RS + j8 * 8) = ra;
        if (lo) {
            const _Float16 c0 = u2h(pc[3]), c1 = u2h(pc[4]), c2 = u2h(pc[5]);
            const fh8 C0 = {c0, c0, c0, c0, c0, c0, c0, c0};
            const fh8 C1 = {c1, c1, c1, c1, c1, c1, c1, c1};
            const fh8 C2 = {c2, c2, c2, c2, c2, c2, c2, c2};
            fh8 rc = hvc0 * C0 + hvc1 * C1 + hvc2 * C2;
            *(fh8*)(buf + (v0 + 64) * RS + j8 * 8) = rc;
        }
    };
    auto mfmaph = [&](const unsigned short* buf, int cc) {   // 10 MFMA/wave
        const unsigned short* wp =
            W2 + (Sbase + cc * 2) * 4096 + (wv * 16 + r16) * 32 + q * 8;
        const fh8 bf0 = *(const fh8*)(wp);
        const fh8 bf1 = *(const fh8*)(wp + 4096);
        #pragma unroll
        for (int s = 0; s < 2; s++) {
            const int ao = s * 32 + q * 8;
            const fh8 bf = s ? bf1 : bf0;
            #pragma unroll
            for (int m = 0; m < 5; m++) {
                fh8 af = *(const fh8*)(buf + (m * 16 + r16) * RS + ao);
                acc[m] = __builtin_amdgcn_mfma_f32_16x16x32_f16(af, bf, acc[m], 0, 0, 0);
            }
        }
    };

    __syncthreads();                             // cp visible

    // Prologue: bin 0 staged into buffer 0
    loadg(0);
    cwr(pch);
    __syncthreads();

    #pragma unroll 1
    for (int cc = 0; cc < NBIN; cc++) {
        if (cc + 1 < NBIN) loadg(cc + 1);        // gathers in flight over MFMA
        mfmaph(&pch[(cc & 1) * CB], cc);
        if (cc + 1 < NBIN) cwr(&pch[((cc + 1) & 1) * CB]);
        __syncthreads();
    }

    // Partial store. D layout: row = q*4+reg, col = r16. 250*80 = 20000
    // exactly -> no guards. One writer per element per stage.
    if (ks == 0) {
        #pragma unroll
        for (int m = 0; m < 5; m++) {
            const int rb = n0 + m * 16 + q * 4;
            #pragma unroll
            for (int r = 0; r < 4; r++)
                out[(rb + r) * OO + wv * 16 + r16] = acc[m][r];
        }
    } else {
        #pragma unroll
        for (int m = 0; m < 5; m++) {
            const int rb = n0 + m * 16 + q * 4;
            #pragma unroll
            for (int r = 0; r < 4; r++)
                parts[(rb + r) * OO + wv * 16 + r16] = f2h(acc[m][r]);
        }
    }
}

// ---------------------------------------------------------------------------
// Epilogue (v18, unchanged): v = out + part + bg; out = v*rsqrt(sum v^2).
// 32 rows/block, 8 threads/row; lane l owns cols [l*16, l*16+16).
// ---------------------------------------------------------------------------
__global__ __launch_bounds__(256) void norm_kernel(
    float* __restrict__ out, const unsigned short* __restrict__ parts,
    const float* __restrict__ bg) {
    const int tid  = threadIdx.x;
    const int n    = blockIdx.x * 32 + (tid >> 3);
    const int l    = tid & 7;
    const int base = n * OO + l * 16;            // 16-float col slice

    float4 o4[4];
    #pragma unroll
    for (int i = 0; i < 4; i++)
        o4[i] = *(const float4*)(out + base + i * 4);

    u16x8 p0 = *(const u16x8*)(parts + base);
    u16x8 p1 = *(const u16x8*)(parts + base + 8);

    float4 b4[4];
    #pragma unroll
    for (int i = 0; i < 4; i++)
        b4[i] = *(const float4*)(bg + l * 16 + i * 4);

    float v[16];
    float s = 0.f;
    #pragma unroll
    for (int i = 0; i < 16; i++) {
        const float ov = (i & 3) == 0 ? o4[i >> 2].x :
                         (i & 3) == 1 ? o4[i >> 2].y :
                         (i & 3) == 2 ? o4[i >> 2].z : o4[i >> 2].w;
        const float bv = (i & 3) == 0 ? b4[i >> 2].x :
                         (i & 3) == 1 ? b4[i >> 2].y :
                         (i & 3) == 2 ? b4[i >> 2].z : b4[i >> 2].w;
        const float pv = h2f((i < 8) ? p0[i] : p1[i & 7]);
        v[i] = ov + pv + bv;
        s += v[i] * v[i];
    }
    for (int off = 4; off; off >>= 1) s += __shfl_down(s, off, 8);
    const float r = rsqrtf(__shfl(s, 0, 8));
    #pragma unroll
    for (int i = 0; i < 4; i++) {
        float4 w = {v[i * 4] * r, v[i * 4 + 1] * r,
                    v[i * 4 + 2] * r, v[i * 4 + 3] * r};
        *(float4*)(out + base + i * 4) = w;
    }
}

// ---------------------------------------------------------------------------
extern "C" void kernel_launch(void* const* d_in, const int* in_sizes, int n_in,
                              void* d_out, int out_size, void* d_ws, size_t ws_size,
                              hipStream_t stream) {
    const float* x        = (const float*)d_in[0];
    const int*   conn_idx = (const int*)  d_in[1];
    const float* conn_w   = (const float*)d_in[2];
    const float* W1       = (const float*)d_in[3];
    const float* Wg       = (const float*)d_in[4];
    const float* bg       = (const float*)d_in[5];
    float*       out      = (float*)d_out;

    unsigned short* W2    = (unsigned short*)d_ws;         // 655,360 fp16 (1.31 MB)
    unsigned short* hb    = W2 + OO * KTOT;                // 1,280,000 fp16 (2.56 MB)
    unsigned short* parts = hb + NV * HH;                  // 2,560,000 fp16 (5.12 MB)

    hipLaunchKernelGGL(prep_kernel, dim3(128 + NV / 32), dim3(256), 0, stream,
                       Wg, x, W1, W2, hb);
    hipLaunchKernelGGL(geo_kernel, dim3(2 * (NV / NB)), dim3(512), 0, stream,
                       conn_idx, conn_w, W2, hb, out, parts);
    hipLaunchKernelGGL(norm_kernel, dim3(NV / 32), dim3(256), 0, stream,
                       out, parts, bg);
}